// Round 7
// baseline (1250.031 us; speedup 1.0000x reference)
//
#include <hip/hip_runtime.h>

// 2-layer stacked LSTM: B=256, T=2048, H=64, layer2 hidden=1.
//
// Round-10: EXIT THE SYNC FABRIC. Evidence R0-R6: every design with a
// per-step __syncthreads + cross-wave LDS h-exchange lands at 1100-1280us
// (~1400cy/step) regardless of residency/gather/wave-count; VALU issue is
// only ~350cy of that -> ~1000cy/step is barrier+LDS+waitcnt mechanics.
// R2 proved the single-wave structure (no barrier; same-wave DS is
// in-order so the h round-trip is raceless) but spilled (256 f32
// weights/lane vs ~184 grant).
//
// Fix demand, not grant: the 64x256 h-weight panel is held as PACKED F16
// PAIRS (128 VGPRs) and the h-dot uses v_dot2_f32_f16 (f32 accumulate).
// h1 is exchanged as packed f16 via a 128B LDS buffer (ds_write_b16 ->
// 32 broadcast b32 reads next step, same wave, in-order -> NO BARRIER).
// x path, biases, c1/c2 chains, layer 2: all f32. Layer 2 = R2's proven
// head (DPP row-reduce) / tail (readlane combine, deferred one step).
// Output stored directly from lane 0 per step: with no barrier there is
// no vmcnt drain to pay. LDS = 8.4KB (x row + h16). One wave per block,
// 256 blocks = 1 wave/CU.
constexpr int kT = 2048;
constexpr int kB = 256;
constexpr int kH = 64;

typedef __attribute__((ext_vector_type(2))) _Float16 f16x2;
typedef __attribute__((ext_vector_type(4))) float f32x4;

__device__ __forceinline__ float fast_sig(float x) {
    return __builtin_amdgcn_rcpf(1.0f + __expf(-x));
}
__device__ __forceinline__ float fast_tanh(float x) {
    float t = __expf(2.0f * x);
    return 1.0f - 2.0f * __builtin_amdgcn_rcpf(t + 1.0f);
}
__device__ __forceinline__ float rl(float v, int lane) {
    return __int_as_float(__builtin_amdgcn_readlane(__float_as_int(v), lane));
}
__device__ __forceinline__ float fdot2(f16x2 a, f16x2 b, float c) {
#if __has_builtin(__builtin_amdgcn_fdot2)
    return __builtin_amdgcn_fdot2(a, b, c, false);
#else
    float d;
    asm volatile("v_dot2_f32_f16 %0, %1, %2, %3"
                 : "=v"(d) : "v"(a), "v"(b), "v"(c));
    return d;
#endif
}
// One butterfly level as a DPP add (VALU pipe, no LDS).
template <int CTRL>
__device__ __forceinline__ float dpp_add(float v) {
    int t = __builtin_amdgcn_update_dpp(0, __float_as_int(v), CTRL, 0xF, 0xF, true);
    return v + __int_as_float(t);
}
// All 16 lanes of each row end with the row sum. (Proven in R2.)
__device__ __forceinline__ float row_reduce16(float v) {
    v = dpp_add<0xB1>(v);   // quad_perm [1,0,3,2]  (xor 1)
    v = dpp_add<0x4E>(v);   // quad_perm [2,3,0,1]  (xor 2)
    v = dpp_add<0x141>(v);  // row_half_mirror      (8-group sum)
    v = dpp_add<0x140>(v);  // row_mirror           (16-group sum)
    return v;
}

// 8 packed-pair loads from h16_lds, and 32 dot2s consuming one 8-chunk.
#define LOAD8(dst, base)                                    \
    _Pragma("unroll") for (int j = 0; j < 8; ++j) dst[j] = h16_lds[(base) + j];
#define DOT8(buf, base)                                     \
    _Pragma("unroll") for (int j = 0; j < 8; ++j) {         \
        z0 = fdot2(buf[j], wh2[0][(base) + j], z0);         \
        z1 = fdot2(buf[j], wh2[1][(base) + j], z1);         \
        z2 = fdot2(buf[j], wh2[2][(base) + j], z2);         \
        z3 = fdot2(buf[j], wh2[3][(base) + j], z3); }

__global__ __launch_bounds__(64)
__attribute__((amdgpu_waves_per_eu(1, 1)))
void lstm2_kernel(
    const float* __restrict__ x, const float* __restrict__ W1,
    const float* __restrict__ b1, const float* __restrict__ W2,
    const float* __restrict__ b2, float* __restrict__ out)
{
    __shared__ f32x4 x4_lds[kT / 4];     // 8 KB: whole input row
    __shared__ f16x2 h16_lds[kH / 2];    // 128 B: h1(t-1) as packed f16 pairs
    float* x_lds = (float*)x4_lds;

    const int l = threadIdx.x;           // lane == layer-1 unit id
    const int b = blockIdx.x;
    const f32x4* xg4 = (const f32x4*)(x + (size_t)b * kT);
    float* outg = out + (size_t)b * kT;

    for (int i = l; i < kT / 4; i += 64) x4_lds[i] = xg4[i];
    ((_Float16*)h16_lds)[l] = (_Float16)0.0f;

    // ---- layer-1 weights: unit l, all 4 gates; h-panel packed f16 ----
    // wh2[g][j] = (W1[2j+1][col], W1[2j+2][col]) pairs h16_lds[j] = (h[2j],h[2j+1]).
    f16x2 wh2[4][32];
    float w0g[4], bg[4], w2r[4];
    #pragma unroll
    for (int g = 0; g < 4; ++g) {
        const int col = g * 64 + l;      // gate-major: i, j, f, o quarters
        w0g[g] = W1[col];
        bg[g]  = b1[col];
        #pragma unroll
        for (int j = 0; j < 32; ++j) {
            f16x2 p;
            p.x = (_Float16)W1[(2 * j + 1) * 256 + col];
            p.y = (_Float16)W1[(2 * j + 2) * 256 + col];
            wh2[g][j] = p;
        }
        w2r[g] = W2[l * 4 + g];          // layer-2 weight for h1[l], gate g
    }
    const f32x4 w2t = ((const f32x4*)W2)[kH];  // W2[64][0..3]: h2 recurrent row
    const f32x4 b2v = ((const f32x4*)b2)[0];

    // ---- PIN the f16 weight panel (blocks rematerialization) ----
    #pragma unroll
    for (int g = 0; g < 4; ++g)
        #pragma unroll
        for (int j = 0; j < 32; ++j) asm volatile("" : "+v"(wh2[g][j]));

    float c1 = 0.0f, c2 = 0.0f, h2 = 0.0f;
    float r0 = 0.0f, r1 = 0.0f, r2 = 0.0f, r3 = 0.0f;  // staged row sums

    #pragma unroll 1
    for (int t = 0; t < kT; ++t) {
        const float xt = x_lds[t];
        f16x2 ha[8], hb[8];
        LOAD8(ha, 0);                    // issue first h chunk

        // ---- layer-2 tail for t-1 (VALU; overlaps the DS latency) ----
        if (t != 0) {
            const float zi = rl(r0,0)+rl(r0,16)+rl(r0,32)+rl(r0,48) + b2v.x + h2 * w2t.x;
            const float zj = rl(r1,0)+rl(r1,16)+rl(r1,32)+rl(r1,48) + b2v.y + h2 * w2t.y;
            const float zf = rl(r2,0)+rl(r2,16)+rl(r2,32)+rl(r2,48) + b2v.z + h2 * w2t.z;
            const float zo = rl(r3,0)+rl(r3,16)+rl(r3,32)+rl(r3,48) + b2v.w + h2 * w2t.w;
            c2 = fast_sig(zf + 1.0f) * c2 + fast_sig(zi) * fast_tanh(zj);
            h2 = fast_sig(zo) * fast_tanh(c2);
            if (l == 0) outg[t - 1] = h2;   // fire-and-forget: no barrier -> no drain
        }

        // ---- layer-1: z[g] = b + x*w0 + dot2(h-pairs, w-pairs), pipelined --
        float z0 = fmaf(xt, w0g[0], bg[0]);
        float z1 = fmaf(xt, w0g[1], bg[1]);
        float z2 = fmaf(xt, w0g[2], bg[2]);
        float z3 = fmaf(xt, w0g[3], bg[3]);
        LOAD8(hb, 8);   DOT8(ha, 0);
        LOAD8(ha, 16);  DOT8(hb, 8);
        LOAD8(hb, 24);  DOT8(ha, 16);
                        DOT8(hb, 24);

        const float gi = fast_sig (z0);
        const float gj = fast_tanh(z1);
        const float gf = fast_sig (z2 + 1.0f);   // forget bias
        const float go = fast_sig (z3);
        c1 = fmaf(gf, c1, gi * gj);
        const float h1own = go * fast_tanh(c1);
        ((_Float16*)h16_lds)[l] = (_Float16)h1own;  // publish for t+1 (in-order)

        // ---- layer-2 head: products + in-row DPP reduce (consumed at t+1) --
        r0 = row_reduce16(h1own * w2r[0]);
        r1 = row_reduce16(h1own * w2r[1]);
        r2 = row_reduce16(h1own * w2r[2]);
        r3 = row_reduce16(h1own * w2r[3]);
    }

    // ---- final layer-2 tail (t == kT) ----
    {
        const float zi = rl(r0,0)+rl(r0,16)+rl(r0,32)+rl(r0,48) + b2v.x + h2 * w2t.x;
        const float zj = rl(r1,0)+rl(r1,16)+rl(r1,32)+rl(r1,48) + b2v.y + h2 * w2t.y;
        const float zf = rl(r2,0)+rl(r2,16)+rl(r2,32)+rl(r2,48) + b2v.z + h2 * w2t.z;
        const float zo = rl(r3,0)+rl(r3,16)+rl(r3,32)+rl(r3,48) + b2v.w + h2 * w2t.w;
        c2 = fast_sig(zf + 1.0f) * c2 + fast_sig(zi) * fast_tanh(zj);
        h2 = fast_sig(zo) * fast_tanh(c2);
        if (l == 0) outg[kT - 1] = h2;
    }
}

extern "C" void kernel_launch(void* const* d_in, const int* in_sizes, int n_in,
                              void* d_out, int out_size, void* d_ws, size_t ws_size,
                              hipStream_t stream) {
    const float* x  = (const float*)d_in[0];
    const float* W1 = (const float*)d_in[1];
    const float* b1 = (const float*)d_in[2];
    const float* W2 = (const float*)d_in[3];
    const float* b2 = (const float*)d_in[4];
    float* out = (float*)d_out;
    lstm2_kernel<<<kB, 64, 0, stream>>>(x, W1, b1, W2, b2, out);
}